// Round 16
// baseline (301.074 us; speedup 1.0000x reference)
//
#include <hip/hip_runtime.h>

#define VOCAB 65536
#define NELEM 4194304      // 256*16*32*32
#define BHW   262144       // 256*1024
#define RS    34           // hupd row stride in doubles (even -> rows 16B-aligned)
#define CH    (RS * 32)    // doubles per channel

__device__ __forceinline__ double cubic_d(double t) {
  const double a = -0.75;
  t = fabs(t);
  if (t <= 1.0) return ((a + 2.0) * t - (a + 3.0)) * t * t + 1.0;
  if (t < 2.0)  return a * (((t - 5.0) * t + 8.0) * t - 4.0);
  return 0.0;
}

// PN=32 idx slot: XOR swizzle, bijective, conflict-free both directions.
__device__ __forceinline__ int idx32_slot(int x, int y) { return (x << 5) | ((y ^ x) & 31); }

// 512 threads: x0=(t&3)*8, y=(t>>2)&31, g=t>>7 (wave-uniform, SGPR) owns ch 4g..4g+3.
// fhat/upsample/conv chains bit-identical to r11; cell sums f64-reassociated (shuffles).
// Wave w covers y in [16*(w&1), 16*(w&1)+15]; lane = ((y&15)<<2)|xq.
template<int PN>
__device__ __forceinline__ void process_scale(
    int si, int phi_idx,
    const float* __restrict__ phi_w, const float* __restrict__ phi_b,
    float* __restrict__ hist, double* __restrict__ acc,
    const float (&fown)[4][8], double (&fhat)[4][8],
    double* __restrict__ hupd, unsigned* __restrict__ idxL,
    float* __restrict__ wMT, double* __restrict__ red, double* __restrict__ pn1buf,
    int t, int y, int g, int x0)
{
  constexpr int CELLS = PN * PN;
  const int w = t >> 6;   // 8 waves

  // ---------- Q: wM build + resid/entropy/psum/prev-mse + cell signs (registers) ----------
  if constexpr (PN != 32) {
    if (t < 32) {
      #pragma unroll
      for (int q = 0; q < PN; ++q) wMT[q * 32 + t] = 0.0f;
      double xp = ((double)t + 0.5) * (double)PN / 32.0 - 0.5;
      int q0i = (int)floor(xp);
      for (int k = 0; k < 4; ++k) {
        int j = q0i + k - 1;
        int jc = j < 0 ? 0 : (j > PN - 1 ? PN - 1 : j);
        wMT[jc * 32 + t] += (float)cubic_d(xp - (double)j);   // f32 accumulate == np M build
      }
    }
  }
  {
    double mseP = 0.0;
    float entf = 0.0f, ps0 = 0, ps1 = 0, ps2 = 0, ps3 = 0;
    unsigned bm0 = 0, bm1 = 0, bm2 = 0, bm3 = 0;   // cell masks (PN<=16 paths)
    unsigned bb[8] = {0, 0, 0, 0, 0, 0, 0, 0};     // PN==32 per-pixel masks
    #pragma unroll
    for (int cc = 0; cc < 4; ++cc) {
      double r[8];
      float psl = 0.0f;
      #pragma unroll
      for (int k = 0; k < 8; ++k) {
        double xr = (double)fown[cc][k] - fhat[cc][k];
        r[k] = xr;
        mseP += xr * xr;                                       // prev scale's mse term
        float pr = 1.0f / (1.0f + __expf(400.0f * (float)xr)); // sigmoid(-400 x)
        entf -= pr * __logf(pr + 1e-5f) + (1.0f - pr) * __logf(1.0f - pr + 1e-5f);
        psl += pr;
      }
      if (cc == 0) ps0 = psl; else if (cc == 1) ps1 = psl; else if (cc == 2) ps2 = psl; else ps3 = psl;

      if constexpr (PN == 32) {
        #pragma unroll
        for (int k = 0; k < 8; ++k)
          if (r[k] > 0.0) bb[k] |= (1u << cc);
      } else if constexpr (PN == 16) {
        #pragma unroll
        for (int j = 0; j < 4; ++j) {
          double s = r[2 * j] + r[2 * j + 1];
          s += __shfl_xor(s, 4);                               // y pair
          if (s > 0.0) {
            unsigned b = 1u << (4 * g + cc);
            if (j == 0) bm0 |= b; else if (j == 1) bm1 |= b; else if (j == 2) bm2 |= b; else bm3 |= b;
          }
        }
      } else if constexpr (PN == 8) {
        double sA = ((r[0] + r[1]) + (r[2] + r[3]));
        double sB = ((r[4] + r[5]) + (r[6] + r[7]));
        sA += __shfl_xor(sA, 4); sA += __shfl_xor(sA, 8);      // 4 y rows
        sB += __shfl_xor(sB, 4); sB += __shfl_xor(sB, 8);
        if (sA > 0.0) bm0 |= 1u << (4 * g + cc);
        if (sB > 0.0) bm1 |= 1u << (4 * g + cc);
      } else if constexpr (PN == 4) {
        double s = ((r[0] + r[1]) + (r[2] + r[3])) + ((r[4] + r[5]) + (r[6] + r[7]));
        s += __shfl_xor(s, 4); s += __shfl_xor(s, 8); s += __shfl_xor(s, 16);   // 8 y rows
        if (s > 0.0) bm0 |= 1u << (4 * g + cc);
      } else if constexpr (PN == 2) {
        double s = ((r[0] + r[1]) + (r[2] + r[3])) + ((r[4] + r[5]) + (r[6] + r[7]));
        s += __shfl_xor(s, 1);                                  // xq pair (16 x)
        s += __shfl_xor(s, 4); s += __shfl_xor(s, 8);
        s += __shfl_xor(s, 16); s += __shfl_xor(s, 32);         // 16 y rows
        if (s > 0.0) bm0 |= 1u << (4 * g + cc);
      } else {  // PN == 1
        double s = ((r[0] + r[1]) + (r[2] + r[3])) + ((r[4] + r[5]) + (r[6] + r[7]));
        s += __shfl_xor(s, 1); s += __shfl_xor(s, 2);           // all 4 xq
        s += __shfl_xor(s, 4); s += __shfl_xor(s, 8);
        s += __shfl_xor(s, 16); s += __shfl_xor(s, 32);         // 16 y rows (half image)
        if ((t & 63) == 0) pn1buf[w * 4 + cc] = s;              // per-wave partial
      }
    }
    // idx writes (idxL zeroed by previous scale's P4; barrier at scale end)
    if constexpr (PN == 32) {
      #pragma unroll
      for (int k = 0; k < 8; ++k)
        if (bb[k]) atomicOr(&idxL[idx32_slot(x0 + k, y)], bb[k] << (4 * g));
    } else if constexpr (PN == 16) {
      if ((y & 1) == 0) {
        int cb = (y >> 1) * 16 + (x0 >> 1);
        if (bm0) atomicOr(&idxL[cb + 0], bm0);
        if (bm1) atomicOr(&idxL[cb + 1], bm1);
        if (bm2) atomicOr(&idxL[cb + 2], bm2);
        if (bm3) atomicOr(&idxL[cb + 3], bm3);
      }
    } else if constexpr (PN == 8) {
      if ((y & 3) == 0) {
        int cb = (y >> 2) * 8 + (x0 >> 2);
        if (bm0) atomicOr(&idxL[cb + 0], bm0);
        if (bm1) atomicOr(&idxL[cb + 1], bm1);
      }
    } else if constexpr (PN == 4) {
      if ((y & 7) == 0) {
        if (bm0) atomicOr(&idxL[(y >> 3) * 4 + (x0 >> 3)], bm0);
      }
    } else if constexpr (PN == 2) {
      if ((y & 15) == 0 && (x0 & 8) == 0) {
        if (bm0) atomicOr(&idxL[(y >> 4) * 2 + (x0 >> 4)], bm0);
      }
    }
    // block reductions -> red
    double ent_d = (double)entf;
    #pragma unroll
    for (int off = 32; off > 0; off >>= 1) {
      mseP  += __shfl_down(mseP, off);
      ent_d += __shfl_down(ent_d, off);
      ps0 += __shfl_down(ps0, off); ps1 += __shfl_down(ps1, off);
      ps2 += __shfl_down(ps2, off); ps3 += __shfl_down(ps3, off);
    }
    if ((t & 63) == 0) {
      red[w * 8 + 0] = mseP; red[w * 8 + 1] = ent_d;
      red[w * 8 + 2] = (double)ps0; red[w * 8 + 3] = (double)ps1;
      red[w * 8 + 4] = (double)ps2; red[w * 8 + 5] = (double)ps3;
    }
  }
  __syncthreads();

  if constexpr (PN == 1) {   // combine the two wave-halves per channel, publish idx
    if (t == 0) {
      unsigned idx = 0;
      for (int c = 0; c < 16; ++c) {
        double tot = pn1buf[(2 * (c >> 2)) * 4 + (c & 3)] + pn1buf[(2 * (c >> 2) + 1) * 4 + (c & 3)];
        if (tot > 0.0) idx |= (1u << c);
      }
      idxL[0] = idx;
      atomicAdd(&hist[idx], 1.0f);
    }
    __syncthreads();
  }

  // ---------- region 2: flush reductions + hist + upsample -> hupd ----------
  if (t == 0) {
    double m = 0.0, e = 0.0;
    #pragma unroll
    for (int ww = 0; ww < 8; ++ww) { m += red[ww * 8]; e += red[ww * 8 + 1]; }
    if (si > 0) atomicAdd(&acc[(si - 1) * 18 + 0], m);
    atomicAdd(&acc[si * 18 + 1], e);
  }
  if (t < 16) {
    int gg = t >> 2, cc = t & 3;
    atomicAdd(&acc[si * 18 + 2 + t], red[(2 * gg) * 8 + 2 + cc] + red[(2 * gg + 1) * 8 + 2 + cc]);
  }
  if constexpr (PN == 32) {
    atomicAdd(&hist[5 * VOCAB + idxL[t]], 1.0f);         // swizzle bijective
    atomicAdd(&hist[5 * VOCAB + idxL[t + 512]], 1.0f);
  } else if constexpr (PN != 1) {
    if (t < CELLS) atomicAdd(&hist[(size_t)si * VOCAB + idxL[t]], 1.0f);
  }
  {
    int c2 = t >> 5, y2 = t & 31;
    double* hrow = hupd + c2 * CH + y2 * RS;
    if constexpr (PN == 32) {
      #pragma unroll
      for (int x = 0; x < 32; ++x)
        hrow[x] = ((idxL[idx32_slot(x, y2)] >> c2) & 1) ? 1.0 : -1.0;
    } else {
      constexpr int QC = (PN < 4) ? PN : 4;
      #pragma unroll
      for (int q0 = 0; q0 < PN; q0 += QC) {
        double tmp[QC];
        #pragma unroll
        for (int qq = 0; qq < QC; ++qq) tmp[qq] = 0.0;
        #pragma unroll
        for (int r = 0; r < PN; ++r) {
          double ww = (double)wMT[r * 32 + y2];
          #pragma unroll
          for (int qq = 0; qq < QC; ++qq) {
            double sg = ((idxL[r * PN + q0 + qq] >> c2) & 1) ? 1.0 : -1.0;
            tmp[qq] = fma(ww, sg, tmp[qq]);
          }
        }
        #pragma unroll
        for (int x = 0; x < 32; ++x) {
          double s2 = (q0 == 0) ? 0.0 : hrow[x];
          #pragma unroll
          for (int qq = 0; qq < QC; ++qq)
            s2 = fma((double)wMT[(q0 + qq) * 32 + x], tmp[qq], s2);
          hrow[x] = s2;
        }
      }
    }
  }
  __syncthreads();

  // ---------- P4: seed fhat, conv3x3 into fhat (0.5-scaled weights, SGPR) ----------
  idxL[t] = 0u; idxL[t + 512] = 0u;                // for next scale's Q (barrier below)
  const float* wgbase = phi_w + phi_idx * 2304;    // wave-uniform -> scalar loads
  #pragma unroll
  for (int cc = 0; cc < 4; ++cc) {
    double bh = 0.5 * (double)phi_b[phi_idx * 16 + 4 * g + cc];
    const double* hu = hupd + (4 * g + cc) * CH + y * RS + x0;
    #pragma unroll
    for (int k = 0; k < 8; ++k)
      fhat[cc][k] = fhat[cc][k] + 0.5 * hu[k] + bh;
  }
  for (int ci = 0; ci < 16; ++ci) {
    const double* hbase = hupd + ci * CH;
    #pragma unroll
    for (int dy = 0; dy < 3; ++dy) {
      int ry = y + dy - 1;
      if (ry < 0 || ry > 31) continue;
      const double* hr = hbase + ry * RS;
      double prow[10];
      prow[0] = (x0 == 0)  ? 0.0 : hr[x0 - 1];
      {
        const double2* hp2 = (const double2*)(hr + x0);   // 16B-aligned (RS even, x0 even)
        double2 p01 = hp2[0], p23 = hp2[1], p45 = hp2[2], p67 = hp2[3];
        prow[1] = p01.x; prow[2] = p01.y; prow[3] = p23.x; prow[4] = p23.y;
        prow[5] = p45.x; prow[6] = p45.y; prow[7] = p67.x; prow[8] = p67.y;
      }
      prow[9] = (x0 == 24) ? 0.0 : hr[x0 + 8];
      #pragma unroll
      for (int cc = 0; cc < 4; ++cc) {
        const float* wp = wgbase + ((4 * g + cc) * 16 + ci) * 9 + dy * 3;  // SGPR addr
        double w0 = 0.5 * (double)wp[0], w1 = 0.5 * (double)wp[1], w2 = 0.5 * (double)wp[2];
        #pragma unroll
        for (int k = 0; k < 8; ++k)
          fhat[cc][k] = fma(w0, prow[k], fma(w1, prow[k + 1], fma(w2, prow[k + 2], fhat[cc][k])));
      }
    }
  }
  __syncthreads();
}

__global__ __launch_bounds__(512) void lfq_all(
    const float* __restrict__ f, const float* __restrict__ phi_w,
    const float* __restrict__ phi_b, float* __restrict__ fhi,
    float* __restrict__ hist, double* __restrict__ acc)
{
  __shared__ double   hupd[16 * CH];     // 139264 B (34-stride rows, 16B-aligned)
  __shared__ unsigned idxL[1024];
  __shared__ float    wMT[512];          // bicubic M transposed [PN][32]
  __shared__ double   red[64];           // 8 waves x 8 slots
  __shared__ double   pn1buf[32];        // PN==1 per-wave partials

  const int t = threadIdx.x;
  const int y = (t >> 2) & 31;
  const int x0 = (t & 3) * 8;
  const int g = __builtin_amdgcn_readfirstlane(t >> 7);   // wave-uniform -> SGPR
  const size_t ibase = (size_t)blockIdx.x * 16384;
  const int w = t >> 6;

  float fown[4][8];
  double fhat[4][8];
  #pragma unroll
  for (int cc = 0; cc < 4; ++cc) {
    const float* fp = f + ibase + (size_t)(4 * g + cc) * 1024 + y * 32 + x0;
    float4 fa = *(const float4*)fp;
    float4 fb = *(const float4*)(fp + 4);
    fown[cc][0] = fa.x; fown[cc][1] = fa.y; fown[cc][2] = fa.z; fown[cc][3] = fa.w;
    fown[cc][4] = fb.x; fown[cc][5] = fb.y; fown[cc][6] = fb.z; fown[cc][7] = fb.w;
    #pragma unroll
    for (int k = 0; k < 8; ++k) fhat[cc][k] = 0.0;
  }

  // PHI_IDX = [0,0,1,2,3,3]
  process_scale<1 >(0, 0, phi_w, phi_b, hist, acc, fown, fhat, hupd, idxL, wMT, red, pn1buf, t, y, g, x0);
  process_scale<2 >(1, 0, phi_w, phi_b, hist, acc, fown, fhat, hupd, idxL, wMT, red, pn1buf, t, y, g, x0);
  process_scale<4 >(2, 1, phi_w, phi_b, hist, acc, fown, fhat, hupd, idxL, wMT, red, pn1buf, t, y, g, x0);
  process_scale<8 >(3, 2, phi_w, phi_b, hist, acc, fown, fhat, hupd, idxL, wMT, red, pn1buf, t, y, g, x0);
  process_scale<16>(4, 3, phi_w, phi_b, hist, acc, fown, fhat, hupd, idxL, wMT, red, pn1buf, t, y, g, x0);
  process_scale<32>(5, 3, phi_w, phi_b, hist, acc, fown, fhat, hupd, idxL, wMT, red, pn1buf, t, y, g, x0);

  // final (scale 6) mse
  double mse = 0.0;
  #pragma unroll
  for (int cc = 0; cc < 4; ++cc)
    #pragma unroll
    for (int k = 0; k < 8; ++k) {
      double d = fhat[cc][k] - (double)fown[cc][k];
      mse += d * d;
    }
  #pragma unroll
  for (int off = 32; off > 0; off >>= 1) mse += __shfl_down(mse, off);
  if ((t & 63) == 0) red[w * 8] = mse;
  __syncthreads();
  if (t == 0) {
    double m = 0.0;
    #pragma unroll
    for (int ww = 0; ww < 8; ++ww) m += red[ww * 8];
    atomicAdd(&acc[5 * 18 + 0], m);
  }

  // output
  #pragma unroll
  for (int cc = 0; cc < 4; ++cc) {
    float* op = fhi + ibase + (size_t)(4 * g + cc) * 1024 + y * 32 + x0;
    *(float4*)op = make_float4((float)fhat[cc][0], (float)fhat[cc][1],
                               (float)fhat[cc][2], (float)fhat[cc][3]);
    *(float4*)(op + 4) = make_float4((float)fhat[cc][4], (float)fhat[cc][5],
                                     (float)fhat[cc][6], (float)fhat[cc][7]);
  }
}

__global__ void finalize_total(const double* __restrict__ acc, float* __restrict__ total)
{
  if (threadIdx.x == 0 && blockIdx.x == 0) {
    double vq = 0.0, ent = 0.0;
    for (int si = 0; si < 6; ++si) {
      vq += acc[si * 18 + 0];
      double pse = acc[si * 18 + 1] / (double)BHW;
      double ce = 0.0;
      for (int cc = 0; cc < 16; ++cc) {
        double ap0 = acc[si * 18 + 2 + cc] / (double)BHW;
        double ap1 = 1.0 - ap0;
        ce -= ap0 * log(ap0 + 1e-5) + ap1 * log(ap1 + 1e-5);
      }
      ent += pse - ce;
    }
    *total = (float)(1.25 * vq / ((double)NELEM * 6.0) + (0.1 / 6.0) * ent);
  }
}

extern "C" void kernel_launch(void* const* d_in, const int* in_sizes, int n_in,
                              void* d_out, int out_size, void* d_ws, size_t ws_size,
                              hipStream_t stream)
{
  const float* f     = (const float*)d_in[0];
  const float* phi_w = (const float*)d_in[1];
  const float* phi_b = (const float*)d_in[2];
  float* out   = (float*)d_out;
  float* fhi   = out;                 // fully overwritten
  float* total = out + NELEM;
  float* hist  = out + NELEM + 1;     // 6*65536
  double* acc  = (double*)d_ws;       // 108 doubles

  hipMemsetAsync((void*)(out + NELEM), 0, (size_t)(1 + 6 * VOCAB) * sizeof(float), stream);
  hipMemsetAsync(d_ws, 0, 1024, stream);

  lfq_all<<<256, 512, 0, stream>>>(f, phi_w, phi_b, fhi, hist, acc);
  finalize_total<<<1, 64, 0, stream>>>(acc, total);
}